// Round 3
// baseline (108.034 us; speedup 1.0000x reference)
//
#include <hip/hip_runtime.h>

#define IN_DIM   256
#define OUT_DIM  256
#define NKNOT    19                  // NUM_KNOTS-1 spline segments
#define NCOL     (IN_DIM * NKNOT)    // 4864 "columns" (i,k pairs)
#define X_MIN_C  (-5.0f)
#define H_C      (10.0f / 19.0f)
#define INV_H_C  (19.0f / 10.0f)

__device__ __forceinline__ unsigned short f32_to_bf16(float f) {
    unsigned int u = __float_as_uint(f);
    u += 0x7FFFu + ((u >> 16) & 1u);
    return (unsigned short)(u >> 16);
}
__device__ __forceinline__ float bf16_to_f32(unsigned short h) {
    return __uint_as_float(((unsigned int)h) << 16);
}

// ---------------------------------------------------------------------------
// Kernel 1: transpose + convert
//   coeffs [o=256][c=4864] float4  ->  Ctb [slice=o>>5][c][o&31] ushort4(bf16)
// ---------------------------------------------------------------------------
__global__ __launch_bounds__(256) void transpose_coeffs(
        const float4* __restrict__ src, ushort4* __restrict__ dst) {
    __shared__ float4 tile[64][65];
    const int c0 = (blockIdx.x % 76) * 64;
    const int r0 = (blockIdx.x / 76) * 64;
    const int tx = threadIdx.x & 63;
    const int ty = threadIdx.x >> 6;

    #pragma unroll
    for (int jj = 0; jj < 16; ++jj) {
        const int r = ty * 16 + jj;
        tile[tx][r] = src[(size_t)(r0 + r) * NCOL + (size_t)(c0 + tx)];
    }
    __syncthreads();
    #pragma unroll
    for (int jj = 0; jj < 16; ++jj) {
        const int c = ty * 16 + jj;
        const float4 v = tile[c][tx];
        ushort4 h;
        h.x = f32_to_bf16(v.x); h.y = f32_to_bf16(v.y);
        h.z = f32_to_bf16(v.z); h.w = f32_to_bf16(v.w);
        const int o = r0 + tx;
        dst[(size_t)(o >> 5) * (NCOL * 32) + (size_t)(c0 + c) * 32 + (o & 31)] = h;
    }
}

// ---------------------------------------------------------------------------
// Kernel 2: partial-sum gather.
//   grid = 8 o-slices x 128 bgrps x 2 i-halves = 2048 blocks
//        -> 8 blocks/CU = 32 waves/CU (needs VGPR<=64: __launch_bounds(256,8))
//   block = 32 o x 8 bs threads; each thread sums 128 i's, writes f32 partial.
// ---------------------------------------------------------------------------
__global__ __launch_bounds__(256, 8) void kan_partial(
        const float*   __restrict__ x,
        const ushort4* __restrict__ Ctb,
        float*         __restrict__ part) {   // [2][B][256]
    __shared__ int2 s_tk[8 * 128];   // .x = k*32, .y = t bits (this i-half only)

    const int s    = blockIdx.x & 7;          // o-slice -> XCD round-robin
    const int bgrp = (blockIdx.x >> 3) & 127; // batch group of 8
    const int half = blockIdx.x >> 10;        // i-half
    const int tid  = threadIdx.x;

    // Phase 1: stage {k*32, t} for 8 rows x 128 i's. 256 thr = 2 rows x 128 i.
    {
        const int row0 = tid >> 7;            // 0..1
        const int col  = tid & 127;           // i within half
        const int i_g  = half * 128 + col;    // global i
        #pragma unroll
        for (int bs = row0; bs < 8; bs += 2) {
            const float xv = x[(bgrp * 8 + bs) * IN_DIM + i_g];
            const float f  = (xv - X_MIN_C) * INV_H_C;
            int idx = (int)floorf(f);
            idx = idx < 0 ? 0 : (idx > NKNOT - 1 ? NKNOT - 1 : idx);
            s_tk[bs * 128 + col] =
                make_int2(idx * 32, __float_as_int(xv - (X_MIN_C + (float)idx * H_C)));
        }
    }
    __syncthreads();

    const int o_l = tid & 31;
    const int bs  = tid >> 5;
    // base points at (slice s, i = half*128, o_l); per-i stride = 19*32 elems
    const ushort4* base = Ctb + (size_t)s * (NCOL * 32)
                              + (size_t)(half * 128) * (NKNOT * 32) + o_l;
    const int2* tk = s_tk + bs * 128;

    float acc0 = 0.f, acc1 = 0.f, acc2 = 0.f, acc3 = 0.f;

    #pragma unroll 4
    for (int i = 0; i < 128; i += 4) {
        const int2 tk0 = tk[i + 0];
        const int2 tk1 = tk[i + 1];
        const int2 tk2 = tk[i + 2];
        const int2 tk3 = tk[i + 3];
        const ushort4 u0 = base[(i + 0) * (NKNOT * 32) + tk0.x];
        const ushort4 u1 = base[(i + 1) * (NKNOT * 32) + tk1.x];
        const ushort4 u2 = base[(i + 2) * (NKNOT * 32) + tk2.x];
        const ushort4 u3 = base[(i + 3) * (NKNOT * 32) + tk3.x];
        const float t0 = __int_as_float(tk0.y);
        const float t1 = __int_as_float(tk1.y);
        const float t2 = __int_as_float(tk2.y);
        const float t3 = __int_as_float(tk3.y);
        acc0 += ((bf16_to_f32(u0.w) * t0 + bf16_to_f32(u0.z)) * t0 + bf16_to_f32(u0.y)) * t0 + bf16_to_f32(u0.x);
        acc1 += ((bf16_to_f32(u1.w) * t1 + bf16_to_f32(u1.z)) * t1 + bf16_to_f32(u1.y)) * t1 + bf16_to_f32(u1.x);
        acc2 += ((bf16_to_f32(u2.w) * t2 + bf16_to_f32(u2.z)) * t2 + bf16_to_f32(u2.y)) * t2 + bf16_to_f32(u2.x);
        acc3 += ((bf16_to_f32(u3.w) * t3 + bf16_to_f32(u3.z)) * t3 + bf16_to_f32(u3.y)) * t3 + bf16_to_f32(u3.x);
    }

    const int b = bgrp * 8 + bs;
    part[(size_t)half * (1024 * OUT_DIM) + (size_t)b * OUT_DIM + s * 32 + o_l] =
        (acc0 + acc1) + (acc2 + acc3);
}

// ---------------------------------------------------------------------------
// Kernel 3: out = part[0] + part[1] + bias   (float4-vectorized)
// ---------------------------------------------------------------------------
__global__ __launch_bounds__(256) void kan_reduce(
        const float4* __restrict__ part,      // [2][B*64] float4
        const float4* __restrict__ bias4,     // [64] float4
        float4*       __restrict__ out,       // [B*64] float4
        int n4) {                             // B*64
    const int n = blockIdx.x * 256 + threadIdx.x;
    if (n < n4) {
        const float4 p0 = part[n];
        const float4 p1 = part[n4 + n];
        const float4 bv = bias4[n & 63];
        float4 r;
        r.x = p0.x + p1.x + bv.x;
        r.y = p0.y + p1.y + bv.y;
        r.z = p0.z + p1.z + bv.z;
        r.w = p0.w + p1.w + bv.w;
        out[n] = r;
    }
}

// ---------------------------------------------------------------------------
extern "C" void kernel_launch(void* const* d_in, const int* in_sizes, int n_in,
                              void* d_out, int out_size, void* d_ws, size_t ws_size,
                              hipStream_t stream) {
    const float* x      = (const float*)d_in[0];   // (B, 256) fp32
    const float* coeffs = (const float*)d_in[1];   // (256, 256, 19, 4) fp32
    const float* bias   = (const float*)d_in[2];   // (256,) fp32
    float*       out    = (float*)d_out;           // (B, 256) fp32

    const int B = in_sizes[0] / IN_DIM;            // 1024
    ushort4* Ctb  = (ushort4*)d_ws;                // 9.96 MB
    float*   part = (float*)((char*)d_ws + (16u << 20)); // 2 x B*256 f32 = 2 MB

    transpose_coeffs<<<304, 256, 0, stream>>>((const float4*)coeffs, Ctb);
    kan_partial<<<2048, 256, 0, stream>>>(x, Ctb, part);
    const int n4 = B * OUT_DIM / 4;
    kan_reduce<<<(n4 + 255) / 256, 256, 0, stream>>>(
        (const float4*)part, (const float4*)bias, (float4*)out, n4);
}

// Round 5
// 99.276 us; speedup vs baseline: 1.0882x; 1.0882x over previous
//
#include <hip/hip_runtime.h>

#define IN_DIM   256
#define OUT_DIM  256
#define NKNOT    19                    // NUM_KNOTS-1 spline segments
#define NCOL     (IN_DIM * NKNOT)      // 4864 (i,k) columns
#define CPQ      1216                  // columns per i-quarter (64*19)
#define SLICE_U4 (CPQ * 32 * 2)        // 77824 uint4 per (o_half,i_quarter) slice
#define X_MIN_C  (-5.0f)
#define H_C      (10.0f / 19.0f)
#define INV_H_C  (19.0f / 10.0f)

// pack two f32 -> bf16 pair (RNE), low = x, high = y
__device__ __forceinline__ unsigned int pk_bf16(float x, float y) {
    unsigned int ux = __float_as_uint(x); ux += 0x7FFFu + ((ux >> 16) & 1u);
    unsigned int uy = __float_as_uint(y); uy += 0x7FFFu + ((uy >> 16) & 1u);
    return (ux >> 16) | (uy & 0xFFFF0000u);
}
__device__ __forceinline__ float lo16(unsigned int u) { return __uint_as_float(u << 16); }
__device__ __forceinline__ float hi16(unsigned int u) { return __uint_as_float(u & 0xFFFF0000u); }

// ---------------------------------------------------------------------------
// Kernel 1: transpose + pack.
//  coeffs [o=256][c=4864] float4 -> per-slice arrays of uint4 PAIRS:
//   slice s = quarter*2 + o_half;  entry (c_local, og): [AB | CD] with
//   AB = {a01,a23,b01,b23}, CD = {c01,c23,d01,d23} (bf16 pairs over 4 o's).
// ---------------------------------------------------------------------------
__global__ __launch_bounds__(256) void transpose_pack(
        const float4* __restrict__ src, uint4* __restrict__ dst) {
    __shared__ float4 tile[64][65];          // [c_local][o_local], +1 pad
    const int c0 = (blockIdx.x % 76) * 64;   // no quarter straddle: 1216 % 64 == 0
    const int r0 = (blockIdx.x / 76) * 64;
    const int tx = threadIdx.x & 63;
    const int ty = threadIdx.x >> 6;

    #pragma unroll
    for (int jj = 0; jj < 16; ++jj) {
        const int r = ty * 16 + jj;
        tile[tx][r] = src[(size_t)(r0 + r) * NCOL + (size_t)(c0 + tx)];
    }
    __syncthreads();

    const int quarter = c0 / CPQ;
    const int clbase  = c0 - quarter * CPQ;
    const int o_half  = r0 >> 7;
    const int og_base = (r0 & 127) >> 2;     // 0 or 16
    uint4* base = dst + (size_t)(quarter * 2 + o_half) * SLICE_U4;

    #pragma unroll
    for (int jj = 0; jj < 4; ++jj) {
        const int p  = jj * 256 + threadIdx.x;
        const int cl = p >> 4;
        const int og = p & 15;
        const float4 v0 = tile[cl][og * 4 + 0];
        const float4 v1 = tile[cl][og * 4 + 1];
        const float4 v2 = tile[cl][og * 4 + 2];
        const float4 v3 = tile[cl][og * 4 + 3];
        uint4 ab, cd;
        ab.x = pk_bf16(v0.x, v1.x); ab.y = pk_bf16(v2.x, v3.x);
        ab.z = pk_bf16(v0.y, v1.y); ab.w = pk_bf16(v2.y, v3.y);
        cd.x = pk_bf16(v0.z, v1.z); cd.y = pk_bf16(v2.z, v3.z);
        cd.z = pk_bf16(v0.w, v1.w); cd.w = pk_bf16(v2.w, v3.w);
        const size_t e = ((size_t)(clbase + cl) * 32 + (og_base + og)) * 2;
        base[e]     = ab;
        base[e + 1] = cd;
    }
}

// ---------------------------------------------------------------------------
// Kernel 2: partial gather+eval. 256 thr = 8 bs x 32 og; thread owns 4 o's.
//  Per i: one tk broadcast + two uint4 loads (32B) -> 4 Horner evals.
//  grid = 8 slices x 128 bgrps = 1024 blocks.
// ---------------------------------------------------------------------------
__global__ __launch_bounds__(256, 4) void kan_partial(
        const float* __restrict__ x,
        const uint4* __restrict__ Ct,
        float4*      __restrict__ part,     // [4][B][64] float4
        int n4q) {                          // B*64
    __shared__ int2 s_tk[8 * 64];           // .x = k*64 (uint4 offset), .y = t bits

    const int s       = blockIdx.x & 7;
    const int o_half  = s & 1;
    const int quarter = s >> 1;
    const int bgrp    = blockIdx.x >> 3;
    const int tid     = threadIdx.x;

    {
        const int col = tid & 63;
        const int row = tid >> 6;
        #pragma unroll
        for (int bs = row; bs < 8; bs += 4) {
            const float xv = x[(bgrp * 8 + bs) * IN_DIM + quarter * 64 + col];
            const float f  = (xv - X_MIN_C) * INV_H_C;
            int idx = (int)floorf(f);
            idx = idx < 0 ? 0 : (idx > NKNOT - 1 ? NKNOT - 1 : idx);
            s_tk[bs * 64 + col] =
                make_int2(idx * 64, __float_as_int(xv - (X_MIN_C + (float)idx * H_C)));
        }
    }
    __syncthreads();

    const int og = tid & 31;
    const int bs = tid >> 5;
    const uint4* base = Ct + (size_t)s * SLICE_U4 + og * 2;
    const int2* tkp = s_tk + bs * 64;

    float y0 = 0.f, y1 = 0.f, y2 = 0.f, y3 = 0.f;

    #pragma unroll 4
    for (int ii = 0; ii < 64; ++ii) {
        const int2 tk = tkp[ii];
        const int  e  = ii * 1216 + tk.x;    // (ii*19 + k) * 64
        const uint4 AB = base[e];
        const uint4 CD = base[e + 1];
        const float t  = __int_as_float(tk.y);
        const float a_0 = lo16(AB.x), a_1 = hi16(AB.x), a_2 = lo16(AB.y), a_3 = hi16(AB.y);
        const float b_0 = lo16(AB.z), b_1 = hi16(AB.z), b_2 = lo16(AB.w), b_3 = hi16(AB.w);
        const float c_0 = lo16(CD.x), c_1 = hi16(CD.x), c_2 = lo16(CD.y), c_3 = hi16(CD.y);
        const float d_0 = lo16(CD.z), d_1 = hi16(CD.z), d_2 = lo16(CD.w), d_3 = hi16(CD.w);
        y0 += ((d_0 * t + c_0) * t + b_0) * t + a_0;
        y1 += ((d_1 * t + c_1) * t + b_1) * t + a_1;
        y2 += ((d_2 * t + c_2) * t + b_2) * t + a_2;
        y3 += ((d_3 * t + c_3) * t + b_3) * t + a_3;
    }

    const int b = bgrp * 8 + bs;
    part[(size_t)quarter * n4q + (size_t)b * 64 + (o_half * 32 + og)] =
        make_float4(y0, y1, y2, y3);
}

// ---------------------------------------------------------------------------
// Kernel 3: out = sum of 4 quarter-partials + bias  (float4)
// ---------------------------------------------------------------------------
__global__ __launch_bounds__(256) void kan_reduce(
        const float4* __restrict__ part,
        const float4* __restrict__ bias4,
        float4*       __restrict__ out,
        int n4) {
    const int n = blockIdx.x * 256 + threadIdx.x;
    if (n < n4) {
        const float4 p0 = part[n];
        const float4 p1 = part[n4 + n];
        const float4 p2 = part[2 * n4 + n];
        const float4 p3 = part[3 * n4 + n];
        const float4 bv = bias4[n & 63];
        float4 r;
        r.x = (p0.x + p1.x) + (p2.x + p3.x) + bv.x;
        r.y = (p0.y + p1.y) + (p2.y + p3.y) + bv.y;
        r.z = (p0.z + p1.z) + (p2.z + p3.z) + bv.z;
        r.w = (p0.w + p1.w) + (p2.w + p3.w) + bv.w;
        out[n] = r;
    }
}

// ---------------------------------------------------------------------------
extern "C" void kernel_launch(void* const* d_in, const int* in_sizes, int n_in,
                              void* d_out, int out_size, void* d_ws, size_t ws_size,
                              hipStream_t stream) {
    const float* x      = (const float*)d_in[0];   // (B, 256) fp32
    const float* coeffs = (const float*)d_in[1];   // (256, 256, 19, 4) fp32
    const float* bias   = (const float*)d_in[2];   // (256,) fp32
    float*       out    = (float*)d_out;           // (B, 256) fp32

    const int B = in_sizes[0] / IN_DIM;            // 1024
    uint4* Ct   = (uint4*)d_ws;                    // 9.96 MB
    float* part = (float*)((char*)d_ws + (16u << 20)); // 4 MB

    transpose_pack<<<304, 256, 0, stream>>>((const float4*)coeffs, Ct);

    const int n4 = B * OUT_DIM / 4;                // B*64
    kan_partial<<<B, 256, 0, stream>>>(x, Ct, (float4*)part, n4);
    kan_reduce<<<(n4 + 255) / 256, 256, 0, stream>>>(
        (const float4*)part, (const float4*)bias, (float4*)out, n4);
}